// Round 14
// baseline (246.624 us; speedup 1.0000x reference)
//
#include <hip/hip_runtime.h>

#define NN 50000
#define CAP 32          // per-node bin capacity (semantics unchanged)
#define OVF_LDS 1024    // per-shard LDS overflow list
#define SHARD_W 64      // 64-node shards
#define NSH 782         // ceil(50000/64)
#define NPB 512         // R6-proven

__device__ __forceinline__ unsigned short f2bf(float f) {
    unsigned u = __float_as_uint(f);
    u += 0x7fffu + ((u >> 16) & 1u);           // round-to-nearest-even
    return (unsigned short)(u >> 16);
}
__device__ __forceinline__ float bf2f(unsigned short u) {
    return __uint_as_float(((unsigned)u) << 16);
}

// ---- R25: uint4 gather (16B/lane, 8 rows/step) + total_pass folded into
// blockbase (lane-63 inclusive scan IS the row total; partition adds sbase
// at lbase stage). R24 = 237.2us best; gather proved issue-bound (uint2 won),
// so widen to the 16B/lane coalescing max. 9 -> 8 launches. ----

__global__ __launch_bounds__(256) void shard_hist(
    const float* __restrict__ x, unsigned short* __restrict__ xb,
    const int* __restrict__ ei0, int E0,
    const int* __restrict__ ei1, int E1,
    unsigned short* __restrict__ hist16)        // [2][NSH][NPB] (aliases aggb)
{
    // P0: x -> bf16 (grid-strided; xb not consumed until aggregate L0)
    int gtid = blockIdx.x * 256 + threadIdx.x;
    int gsz  = gridDim.x * 256;
    for (int i = gtid; i < NN * 16; i += gsz) {
        float4 v = ((const float4*)x)[i];
        ushort4 o;
        o.x = f2bf(v.x); o.y = f2bf(v.y); o.z = f2bf(v.z); o.w = f2bf(v.w);
        ((ushort4*)xb)[i] = o;
    }

    __shared__ unsigned lh[NSH];
    int local = blockIdx.x; int rel = 0;
    if (local >= NPB) { local -= NPB; rel = 1; }
    int pb = (local & 7) * (NPB / 8) + (local >> 3);
    const int* ei = rel ? ei1 : ei0;
    int E         = rel ? E1  : E0;
    int ce = (E + NPB - 1) / NPB;
    int lo = pb * ce, hi = min(lo + ce, E);

    for (int i = threadIdx.x; i < NSH; i += 256) lh[i] = 0;
    __syncthreads();
    for (int t = lo + threadIdx.x; t < hi; t += 256)
        atomicAdd(&lh[ei[E + t] >> 6], 1u);
    __syncthreads();
    for (int i = threadIdx.x; i < NSH; i += 256)
        hist16[((size_t)rel * NSH + i) * NPB + pb] = (unsigned short)lh[i];
}

// One wave per (rel,shard): lane-local prefix + shfl_up wave scan.
// R25: writes RELATIVE bases (no sbase dependency) and emits the row total
// (lane-63 inclusive value) — total_pass deleted.
__global__ __launch_bounds__(256) void blockbase_rel(
    const unsigned short* __restrict__ hist16,
    unsigned* __restrict__ pbase,               // [2][NSH][NPB] (aliases aggb)
    int* __restrict__ tot)
{
    int gw = (blockIdx.x * 256 + threadIdx.x) >> 6;
    int lane = threadIdx.x & 63;
    if (gw >= 2 * NSH) return;
    uint4 v = ((const uint4*)(hist16 + (size_t)gw * NPB))[lane];
    unsigned c[8] = {v.x & 0xffffu, v.x >> 16, v.y & 0xffffu, v.y >> 16,
                     v.z & 0xffffu, v.z >> 16, v.w & 0xffffu, v.w >> 16};
    unsigned lsum = 0;
    #pragma unroll
    for (int j = 0; j < 8; j++) lsum += c[j];
    unsigned incl = lsum;
    for (int off = 1; off < 64; off <<= 1) {
        unsigned n = __shfl_up(incl, off);
        if (lane >= off) incl += n;
    }
    unsigned run = incl - lsum;                 // relative to row start
    unsigned* prow = pbase + (size_t)gw * NPB + lane * 8;
    #pragma unroll
    for (int j = 0; j < 8; j++) { prow[j] = run; run += c[j]; }
    if (lane == 63) tot[gw] = (int)incl;
}

// Exclusive scan of 1564 totals -> shard bases (+ sentinel). One block.
__global__ __launch_bounds__(256) void scan_pass(
    const int* __restrict__ tot, int* __restrict__ sbase)
{
    __shared__ int ps[256];
    int t = threadIdx.x;
    int v[7];
    int s = 0;
    #pragma unroll
    for (int j = 0; j < 7; j++) {
        int i = t * 7 + j;
        v[j] = (i < 2 * NSH) ? tot[i] : 0;
        s += v[j];
    }
    ps[t] = s;
    __syncthreads();
    for (int off = 1; off < 256; off <<= 1) {
        int add = (t >= off) ? ps[t - off] : 0;
        __syncthreads();
        ps[t] += add;
        __syncthreads();
    }
    int run = (t == 0) ? 0 : ps[t - 1];
    #pragma unroll
    for (int j = 0; j < 7; j++) {
        int i = t * 7 + j;
        if (i < 2 * NSH) sbase[i] = run;
        run += v[j];
    }
    if (t == 255) sbase[2 * NSH] = run;
}

// Scatter edges into shard-segregated compact array: entry = (dst<<16)|src.
// R25: lbase = relative pbase + sbase[row] (sbase is 6KB, L2-hot).
__global__ __launch_bounds__(256) void partition_pass(
    const int* __restrict__ ei0, int E0,
    const int* __restrict__ ei1, int E1,
    const unsigned* __restrict__ pbase, const int* __restrict__ sbase,
    unsigned* __restrict__ compact)             // [E0+E1] u32 (old bins slot)
{
    __shared__ unsigned lbase[NSH];
    __shared__ unsigned lrank[NSH];
    int local = blockIdx.x; int rel = 0;
    if (local >= NPB) { local -= NPB; rel = 1; }
    int pb = (local & 7) * (NPB / 8) + (local >> 3);
    const int* ei = rel ? ei1 : ei0;
    int E         = rel ? E1  : E0;
    int ce = (E + NPB - 1) / NPB;
    int lo = pb * ce, hi = min(lo + ce, E);

    for (int i = threadIdx.x; i < NSH; i += 256) {
        lbase[i] = pbase[((size_t)rel * NSH + i) * NPB + pb]
                 + (unsigned)sbase[rel * NSH + i];
        lrank[i] = 0;
    }
    __syncthreads();
    for (int t = lo + threadIdx.x; t < hi; t += 256) {
        int dst = ei[E + t];
        int src = ei[t];
        int s = dst >> 6;
        unsigned r = atomicAdd(&lrank[s], 1u);
        compact[lbase[s] + r] = ((unsigned)dst << 16) | (unsigned)src;
    }
}

// Fused bin+aggregate. Phase 1: LDS-sort the contiguous compact segment into
// per-node bins (CAP=32 + local ovf). Phase 2 (R25): uint4 gather — 8 lanes
// per 128B row, 8 rows/step, 2x unroll (16 rows in flight); reduce via
// shfl_xor(8,16,32); lanes 0-7 write the uint4 row. Register accumulation.
__global__ __launch_bounds__(256) void aggregate_shard(
    const unsigned* __restrict__ compact, const int* __restrict__ sbase,
    const unsigned short* __restrict__ hb, unsigned short* __restrict__ agg)
{
    __shared__ unsigned short lbins[SHARD_W * CAP];   // 4KB
    __shared__ unsigned lcnt[SHARD_W];                // 256B
    __shared__ unsigned lovf[OVF_LDS];                // 4KB
    __shared__ unsigned lovf_cnt;

    int bid = blockIdx.x;                       // = rel*NSH + s
    int rel = bid / NSH;
    int s   = bid - rel * NSH;
    int tid = threadIdx.x;
    int lane = tid & 63;
    int oct = lane >> 3;                        // 0..7: row-slot within wave
    int r   = lane & 7;                         // uint4 index within 128B row
    int wid = tid >> 6;                         // 0..3

    if (tid < SHARD_W) lcnt[tid] = 0;
    if (tid == 0) lovf_cnt = 0;
    __syncthreads();

    // Phase 1: LDS bin (identical semantics to bin_pass, local ovf).
    int base = sbase[bid];
    int tt   = sbase[bid + 1] - base;
    for (int j = tid; j < tt; j += 256) {
        unsigned e = compact[base + j];
        int loc = (int)(e >> 16) & (SHARD_W - 1);
        unsigned rr = atomicAdd(&lcnt[loc], 1u);
        if (rr < CAP) {
            lbins[loc * CAP + rr] = (unsigned short)(e & 0xffffu);
        } else {
            unsigned o = atomicAdd(&lovf_cnt, 1u);
            if (o < OVF_LDS) lovf[o] = ((unsigned)loc << 16) | (e & 0xffffu);
        }
    }
    __syncthreads();

    // Phase 2: wide gather; wave w owns nodes w*16..w*16+15.
    const uint4* hb128 = (const uint4*)hb;      // row s = hb128[s*8 + r]
    uint4* agg128 = (uint4*)agg;
    for (int t = 0; t < 16; ++t) {
        int loc = wid * 16 + t;
        int d = (int)lcnt[loc];
        int m = min(d, CAP);
        int idx = 0;
        if (lane < m) idx = lbins[loc * CAP + lane];
        float a0=0.f,a1=0.f,a2=0.f,a3=0.f,a4=0.f,a5=0.f,a6=0.f,a7=0.f;
        float b0=0.f,b1=0.f,b2=0.f,b3=0.f,b4=0.f,b5=0.f,b6=0.f,b7=0.f;
        int steps = (m + 7) >> 3;
        int j = 0;
        for (; j + 2 <= steps; j += 2) {
            int e0 = 8 * j + oct;
            int e1 = 8 * (j + 1) + oct;
            int s0 = __shfl(idx, e0 & 31);
            int s1 = __shfl(idx, e1 & 31);
            uint4 u0 = (e0 < m) ? hb128[(size_t)s0 * 8 + r]
                                : make_uint4(0u, 0u, 0u, 0u);
            uint4 u1 = (e1 < m) ? hb128[(size_t)s1 * 8 + r]
                                : make_uint4(0u, 0u, 0u, 0u);
            a0 += __uint_as_float(u0.x << 16); a1 += __uint_as_float(u0.x & 0xffff0000u);
            a2 += __uint_as_float(u0.y << 16); a3 += __uint_as_float(u0.y & 0xffff0000u);
            a4 += __uint_as_float(u0.z << 16); a5 += __uint_as_float(u0.z & 0xffff0000u);
            a6 += __uint_as_float(u0.w << 16); a7 += __uint_as_float(u0.w & 0xffff0000u);
            b0 += __uint_as_float(u1.x << 16); b1 += __uint_as_float(u1.x & 0xffff0000u);
            b2 += __uint_as_float(u1.y << 16); b3 += __uint_as_float(u1.y & 0xffff0000u);
            b4 += __uint_as_float(u1.z << 16); b5 += __uint_as_float(u1.z & 0xffff0000u);
            b6 += __uint_as_float(u1.w << 16); b7 += __uint_as_float(u1.w & 0xffff0000u);
        }
        for (; j < steps; ++j) {
            int e0 = 8 * j + oct;
            int s0 = __shfl(idx, e0 & 31);
            uint4 u0 = (e0 < m) ? hb128[(size_t)s0 * 8 + r]
                                : make_uint4(0u, 0u, 0u, 0u);
            a0 += __uint_as_float(u0.x << 16); a1 += __uint_as_float(u0.x & 0xffff0000u);
            a2 += __uint_as_float(u0.y << 16); a3 += __uint_as_float(u0.y & 0xffff0000u);
            a4 += __uint_as_float(u0.z << 16); a5 += __uint_as_float(u0.z & 0xffff0000u);
            a6 += __uint_as_float(u0.w << 16); a7 += __uint_as_float(u0.w & 0xffff0000u);
        }
        if (d > CAP) {                 // rare: this shard's local overflow
            int cnt = min((int)lovf_cnt, OVF_LDS);
            for (int e0 = 0; e0 < cnt; ++e0) {
                unsigned v = lovf[e0];
                if ((int)(v >> 16) == loc && oct == 0) {
                    uint4 u = hb128[(size_t)(v & 0xffffu) * 8 + r];
                    a0 += __uint_as_float(u.x << 16); a1 += __uint_as_float(u.x & 0xffff0000u);
                    a2 += __uint_as_float(u.y << 16); a3 += __uint_as_float(u.y & 0xffff0000u);
                    a4 += __uint_as_float(u.z << 16); a5 += __uint_as_float(u.z & 0xffff0000u);
                    a6 += __uint_as_float(u.w << 16); a7 += __uint_as_float(u.w & 0xffff0000u);
                }
            }
        }
        a0 += b0; a1 += b1; a2 += b2; a3 += b3;
        a4 += b4; a5 += b5; a6 += b6; a7 += b7;
        a0 += __shfl_xor(a0, 8); a0 += __shfl_xor(a0, 16); a0 += __shfl_xor(a0, 32);
        a1 += __shfl_xor(a1, 8); a1 += __shfl_xor(a1, 16); a1 += __shfl_xor(a1, 32);
        a2 += __shfl_xor(a2, 8); a2 += __shfl_xor(a2, 16); a2 += __shfl_xor(a2, 32);
        a3 += __shfl_xor(a3, 8); a3 += __shfl_xor(a3, 16); a3 += __shfl_xor(a3, 32);
        a4 += __shfl_xor(a4, 8); a4 += __shfl_xor(a4, 16); a4 += __shfl_xor(a4, 32);
        a5 += __shfl_xor(a5, 8); a5 += __shfl_xor(a5, 16); a5 += __shfl_xor(a5, 32);
        a6 += __shfl_xor(a6, 8); a6 += __shfl_xor(a6, 16); a6 += __shfl_xor(a6, 32);
        a7 += __shfl_xor(a7, 8); a7 += __shfl_xor(a7, 16); a7 += __shfl_xor(a7, 32);
        int node = s * SHARD_W + loc;
        if (lane < 8 && node < NN) {
            float inv = 1.0f / (float)max(d, 1);
            uint4 o;
            o.x = (unsigned)f2bf(a0 * inv) | ((unsigned)f2bf(a1 * inv) << 16);
            o.y = (unsigned)f2bf(a2 * inv) | ((unsigned)f2bf(a3 * inv) << 16);
            o.z = (unsigned)f2bf(a4 * inv) | ((unsigned)f2bf(a5 * inv) << 16);
            o.w = (unsigned)f2bf(a6 * inv) | ((unsigned)f2bf(a7 * inv) << 16);
            agg128[((size_t)rel * NN + node) * 8 + r] = o;
        }
    }
}

// L0: h1b = bf16( relu(mean0@Wl0 + mean1@Wl1 + self@(Wr0+Wr1) + b) ).
#define RST 132
__global__ __launch_bounds__(256) void layer_gemm(
    const unsigned short* __restrict__ agg0, const unsigned short* __restrict__ agg1,
    const unsigned short* __restrict__ selfb,
    const float* __restrict__ Wl0, const float* __restrict__ Wl1,
    const float* __restrict__ Wr0, const float* __restrict__ Wr1,
    const float* __restrict__ b0, const float* __restrict__ b1,
    unsigned short* __restrict__ hb16)
{
    __shared__ float Wch[64 * 64];
    __shared__ float rowsT[64 * RST];
    __shared__ float bias[64];

    int tid = threadIdx.x;
    int base = blockIdx.x * 128;
    if (tid < 64) bias[tid] = b0[tid] + b1[tid];

    int j8 = (tid & 7) * 8;
    int n4 = (tid >> 3) * 4;

    float acc[4][8];
    #pragma unroll
    for (int i = 0; i < 4; i++)
        #pragma unroll
        for (int c = 0; c < 8; c++) acc[i][c] = 0.f;

    for (int chunk = 0; chunk < 3; chunk++) {
        const float* W = (chunk == 0) ? Wl0 : (chunk == 1) ? Wl1 : Wr0;
        const unsigned short* src = (chunk == 0) ? agg0 : (chunk == 1) ? agg1 : selfb;
        __syncthreads();
        #pragma unroll
        for (int r = 0; r < 4; r++) {
            int i = tid + 256 * r;
            float4 w = *(const float4*)&W[i * 4];
            if (chunk == 2) {
                float4 w2 = *(const float4*)&Wr1[i * 4];
                w.x += w2.x; w.y += w2.y; w.z += w2.z; w.w += w2.w;
            }
            *(float4*)&Wch[i * 4] = w;
        }
        #pragma unroll
        for (int r = 0; r < 8; r++) {
            int i = tid + 256 * r;
            int node = i >> 4;
            int k4 = (i & 15) * 4;
            int g = base + node;
            ushort4 u = make_ushort4(0, 0, 0, 0);
            if (g < NN) u = *(const ushort4*)&src[(size_t)g * 64 + k4];
            rowsT[(k4 + 0) * RST + node] = bf2f(u.x);
            rowsT[(k4 + 1) * RST + node] = bf2f(u.y);
            rowsT[(k4 + 2) * RST + node] = bf2f(u.z);
            rowsT[(k4 + 3) * RST + node] = bf2f(u.w);
        }
        __syncthreads();
        #pragma unroll 4
        for (int k = 0; k < 64; k++) {
            float4 wa = *(const float4*)&Wch[k * 64 + j8];
            float4 wb = *(const float4*)&Wch[k * 64 + j8 + 4];
            float4 rv = *(const float4*)&rowsT[k * RST + n4];
            float w[8] = {wa.x, wa.y, wa.z, wa.w, wb.x, wb.y, wb.z, wb.w};
            float rr[4] = {rv.x, rv.y, rv.z, rv.w};
            #pragma unroll
            for (int i = 0; i < 4; i++)
                #pragma unroll
                for (int c = 0; c < 8; c++)
                    acc[i][c] = fmaf(rr[i], w[c], acc[i][c]);
        }
    }

    #pragma unroll
    for (int i = 0; i < 4; i++) {
        int g = base + n4 + i;
        if (g < NN) {
            ushort4 p0, p1;
            p0.x = f2bf(fmaxf(acc[i][0] + bias[j8 + 0], 0.f));
            p0.y = f2bf(fmaxf(acc[i][1] + bias[j8 + 1], 0.f));
            p0.z = f2bf(fmaxf(acc[i][2] + bias[j8 + 2], 0.f));
            p0.w = f2bf(fmaxf(acc[i][3] + bias[j8 + 3], 0.f));
            p1.x = f2bf(fmaxf(acc[i][4] + bias[j8 + 4], 0.f));
            p1.y = f2bf(fmaxf(acc[i][5] + bias[j8 + 5], 0.f));
            p1.z = f2bf(fmaxf(acc[i][6] + bias[j8 + 6], 0.f));
            p1.w = f2bf(fmaxf(acc[i][7] + bias[j8 + 7], 0.f));
            *(ushort4*)&hb16[(size_t)g * 64 + j8]     = p0;
            *(ushort4*)&hb16[(size_t)g * 64 + j8 + 4] = p1;
        }
    }
}

// L1 + final fused: h2 tile in LDS, then out = h2 @ linW + linb.
__global__ __launch_bounds__(256) void layer_gemm_final(
    const unsigned short* __restrict__ agg0, const unsigned short* __restrict__ agg1,
    const unsigned short* __restrict__ selfb,
    const float* __restrict__ Wl0, const float* __restrict__ Wl1,
    const float* __restrict__ Wr0, const float* __restrict__ Wr1,
    const float* __restrict__ b0, const float* __restrict__ b1,
    const float* __restrict__ linW, const float* __restrict__ linb,
    float* __restrict__ out)
{
    __shared__ float Wch[64 * 64];
    __shared__ float rowsT[64 * RST];
    __shared__ float bias[64];

    int tid = threadIdx.x;
    int base = blockIdx.x * 128;
    if (tid < 64) bias[tid] = b0[tid] + b1[tid];

    int j8 = (tid & 7) * 8;
    int n4 = (tid >> 3) * 4;

    float acc[4][8];
    #pragma unroll
    for (int i = 0; i < 4; i++)
        #pragma unroll
        for (int c = 0; c < 8; c++) acc[i][c] = 0.f;

    for (int chunk = 0; chunk < 3; chunk++) {
        const float* W = (chunk == 0) ? Wl0 : (chunk == 1) ? Wl1 : Wr0;
        const unsigned short* src = (chunk == 0) ? agg0 : (chunk == 1) ? agg1 : selfb;
        __syncthreads();
        #pragma unroll
        for (int r = 0; r < 4; r++) {
            int i = tid + 256 * r;
            float4 w = *(const float4*)&W[i * 4];
            if (chunk == 2) {
                float4 w2 = *(const float4*)&Wr1[i * 4];
                w.x += w2.x; w.y += w2.y; w.z += w2.z; w.w += w2.w;
            }
            *(float4*)&Wch[i * 4] = w;
        }
        #pragma unroll
        for (int r = 0; r < 8; r++) {
            int i = tid + 256 * r;
            int node = i >> 4;
            int k4 = (i & 15) * 4;
            int g = base + node;
            ushort4 u = make_ushort4(0, 0, 0, 0);
            if (g < NN) u = *(const ushort4*)&src[(size_t)g * 64 + k4];
            rowsT[(k4 + 0) * RST + node] = bf2f(u.x);
            rowsT[(k4 + 1) * RST + node] = bf2f(u.y);
            rowsT[(k4 + 2) * RST + node] = bf2f(u.z);
            rowsT[(k4 + 3) * RST + node] = bf2f(u.w);
        }
        __syncthreads();
        #pragma unroll 4
        for (int k = 0; k < 64; k++) {
            float4 wa = *(const float4*)&Wch[k * 64 + j8];
            float4 wb = *(const float4*)&Wch[k * 64 + j8 + 4];
            float4 rv = *(const float4*)&rowsT[k * RST + n4];
            float w[8] = {wa.x, wa.y, wa.z, wa.w, wb.x, wb.y, wb.z, wb.w};
            float rr[4] = {rv.x, rv.y, rv.z, rv.w};
            #pragma unroll
            for (int i = 0; i < 4; i++)
                #pragma unroll
                for (int c = 0; c < 8; c++)
                    acc[i][c] = fmaf(rr[i], w[c], acc[i][c]);
        }
    }

    // relu epilogue into registers
    float o[4][8];
    #pragma unroll
    for (int i = 0; i < 4; i++)
        #pragma unroll
        for (int c = 0; c < 8; c++)
            o[i][c] = fmaxf(acc[i][c] + bias[j8 + c], 0.f);

    __syncthreads();   // everyone done reading Wch/rowsT/bias

    // restage: Wch <- linW (64x32), bias <- linb, rowsT <- h2 tile transposed
    #pragma unroll
    for (int r = 0; r < 2; r++) {
        int i = tid + 256 * r;   // 512 float4 = 2048 floats
        *(float4*)&Wch[i * 4] = *(const float4*)&linW[i * 4];
    }
    if (tid < 32) bias[tid] = linb[tid];
    #pragma unroll
    for (int i = 0; i < 4; i++)
        #pragma unroll
        for (int c = 0; c < 8; c++)
            rowsT[(j8 + c) * RST + (n4 + i)] = o[i][c];
    __syncthreads();

    // mini-GEMM: out[128 x 32] = h2_tile @ linW + linb
    int j4 = (tid & 7) * 4;
    float acc2[4][4];
    #pragma unroll
    for (int i = 0; i < 4; i++)
        #pragma unroll
        for (int c = 0; c < 4; c++) acc2[i][c] = 0.f;
    #pragma unroll 4
    for (int k = 0; k < 64; k++) {
        float4 w = *(const float4*)&Wch[k * 32 + j4];
        float4 rv = *(const float4*)&rowsT[k * RST + n4];
        float wr[4] = {w.x, w.y, w.z, w.w};
        float rr[4] = {rv.x, rv.y, rv.z, rv.w};
        #pragma unroll
        for (int i = 0; i < 4; i++)
            #pragma unroll
            for (int c = 0; c < 4; c++)
                acc2[i][c] = fmaf(rr[i], wr[c], acc2[i][c]);
    }
    #pragma unroll
    for (int i = 0; i < 4; i++) {
        int g = base + n4 + i;
        if (g < NN) {
            float4 ov;
            ov.x = acc2[i][0] + bias[j4 + 0];
            ov.y = acc2[i][1] + bias[j4 + 1];
            ov.z = acc2[i][2] + bias[j4 + 2];
            ov.w = acc2[i][3] + bias[j4 + 3];
            *(float4*)&out[(size_t)g * 32 + j4] = ov;
        }
    }
}

extern "C" void kernel_launch(void* const* d_in, const int* in_sizes, int n_in,
                              void* d_out, int out_size, void* d_ws, size_t ws_size,
                              hipStream_t stream)
{
    const float* x    = (const float*)d_in[0];
    const int*   ei0  = (const int*)d_in[1];
    const int*   ei1  = (const int*)d_in[2];
    const float* Wl   = (const float*)d_in[3];   // [2,2,64,64]
    const float* Wr   = (const float*)d_in[4];   // [2,2,64,64]
    const float* bl   = (const float*)d_in[5];   // [2,2,64]
    const float* linW = (const float*)d_in[6];   // [64,32]
    const float* linb = (const float*)d_in[7];   // [32]
    float* out = (float*)d_out;

    int E0 = in_sizes[1] / 2;
    int E1 = in_sizes[2] / 2;

    // Workspace (~32.4MB), R23 layout (compact outlives gemm0):
    // [compact 6.4MB | h1b 6.4MB | aggb 12.8MB | xb 6.4MB | tot/sbase 13KB]
    //   hist16 [2][NSH][NPB] 1.6MB aliases aggb+0      (dead before agg L0)
    //   pbase  [2][NSH][NPB] 3.2MB aliases aggb+1.6M   (dead after partition)
    unsigned*       compact = (unsigned*)d_ws;            // 1.6M u32 = 6.4MB
    unsigned short* h1b  = (unsigned short*)d_ws + (size_t)2 * NN * CAP;
    unsigned short* aggb = h1b + (size_t)NN * 64;
    unsigned short* agg0 = aggb;
    unsigned short* agg1 = aggb + (size_t)NN * 64;
    unsigned short* xb   = aggb + (size_t)2 * NN * 64;
    int*            tot   = (int*)(xb + (size_t)NN * 64);
    int*            sbase = tot + 2 * NSH;

    unsigned short* hist16 = aggb;
    unsigned*       pbase  = (unsigned*)(aggb + (size_t)2 * NSH * NPB);

    dim3 blk(256);
    int ggrid = (NN + 127) / 128;               // 391
    int wave_grid = (2 * NSH * 64 + 255) / 256; // 391: 1 wave/(rel,shard)

    // ---- shard-partition binning (bin fused into agg; total folded) ----
    shard_hist<<<2 * NPB, blk, 0, stream>>>(x, xb, ei0, E0, ei1, E1, hist16);
    blockbase_rel<<<wave_grid, blk, 0, stream>>>(hist16, pbase, tot);
    scan_pass<<<1, blk, 0, stream>>>(tot, sbase);
    partition_pass<<<2 * NPB, blk, 0, stream>>>(ei0, E0, ei1, E1, pbase, sbase,
                                                compact);

    // ---- Layer 0 (fused bin+aggregate from xb; h1b bf16 out) ----
    aggregate_shard<<<2 * NSH, blk, 0, stream>>>(compact, sbase, xb, aggb);
    layer_gemm<<<ggrid, blk, 0, stream>>>(agg0, agg1, xb,
        Wl + 0, Wl + 4096, Wr + 0, Wr + 4096, bl + 0, bl + 64, h1b);

    // ---- Layer 1 + final projection fused (h2 never materialized) ----
    aggregate_shard<<<2 * NSH, blk, 0, stream>>>(compact, sbase, h1b, aggb);
    layer_gemm_final<<<ggrid, blk, 0, stream>>>(agg0, agg1, h1b,
        Wl + 8192, Wl + 12288, Wr + 8192, Wr + 12288, bl + 128, bl + 192,
        linW, linb, out);
}

// Round 15
// 234.577 us; speedup vs baseline: 1.0514x; 1.0514x over previous
//
#include <hip/hip_runtime.h>

#define NN 50000
#define CAP 32          // per-node bin capacity (semantics unchanged)
#define OVF_LDS 1024    // per-shard LDS overflow list
#define SHARD_W 64      // 64-node shards
#define NSH 782         // ceil(50000/64)
#define NPB 512         // R6-proven

__device__ __forceinline__ unsigned short f2bf(float f) {
    unsigned u = __float_as_uint(f);
    u += 0x7fffu + ((u >> 16) & 1u);           // round-to-nearest-even
    return (unsigned short)(u >> 16);
}
__device__ __forceinline__ float bf2f(unsigned short u) {
    return __uint_as_float(((unsigned)u) << 16);
}

// ---- R26: R25's uint4 gather REVERTED to R24's proven uint2 (uint4 went
// VALU-bound: 46% VALUBusy, 24 shfl/node reduce, FETCH +50MB => 50us vs
// uint2's ~30us). KEEPING R25's total_pass->blockbase fold (independent,
// mechanically sound: lane-63 inclusive scan IS the row total). 8 launches.

__global__ __launch_bounds__(256) void shard_hist(
    const float* __restrict__ x, unsigned short* __restrict__ xb,
    const int* __restrict__ ei0, int E0,
    const int* __restrict__ ei1, int E1,
    unsigned short* __restrict__ hist16)        // [2][NSH][NPB] (aliases aggb)
{
    // P0: x -> bf16 (grid-strided; xb not consumed until aggregate L0)
    int gtid = blockIdx.x * 256 + threadIdx.x;
    int gsz  = gridDim.x * 256;
    for (int i = gtid; i < NN * 16; i += gsz) {
        float4 v = ((const float4*)x)[i];
        ushort4 o;
        o.x = f2bf(v.x); o.y = f2bf(v.y); o.z = f2bf(v.z); o.w = f2bf(v.w);
        ((ushort4*)xb)[i] = o;
    }

    __shared__ unsigned lh[NSH];
    int local = blockIdx.x; int rel = 0;
    if (local >= NPB) { local -= NPB; rel = 1; }
    int pb = (local & 7) * (NPB / 8) + (local >> 3);
    const int* ei = rel ? ei1 : ei0;
    int E         = rel ? E1  : E0;
    int ce = (E + NPB - 1) / NPB;
    int lo = pb * ce, hi = min(lo + ce, E);

    for (int i = threadIdx.x; i < NSH; i += 256) lh[i] = 0;
    __syncthreads();
    for (int t = lo + threadIdx.x; t < hi; t += 256)
        atomicAdd(&lh[ei[E + t] >> 6], 1u);
    __syncthreads();
    for (int i = threadIdx.x; i < NSH; i += 256)
        hist16[((size_t)rel * NSH + i) * NPB + pb] = (unsigned short)lh[i];
}

// One wave per (rel,shard): lane-local prefix + shfl_up wave scan.
// Writes RELATIVE bases and emits the row total (lane-63 inclusive value).
__global__ __launch_bounds__(256) void blockbase_rel(
    const unsigned short* __restrict__ hist16,
    unsigned* __restrict__ pbase,               // [2][NSH][NPB] (aliases aggb)
    int* __restrict__ tot)
{
    int gw = (blockIdx.x * 256 + threadIdx.x) >> 6;
    int lane = threadIdx.x & 63;
    if (gw >= 2 * NSH) return;
    uint4 v = ((const uint4*)(hist16 + (size_t)gw * NPB))[lane];
    unsigned c[8] = {v.x & 0xffffu, v.x >> 16, v.y & 0xffffu, v.y >> 16,
                     v.z & 0xffffu, v.z >> 16, v.w & 0xffffu, v.w >> 16};
    unsigned lsum = 0;
    #pragma unroll
    for (int j = 0; j < 8; j++) lsum += c[j];
    unsigned incl = lsum;
    for (int off = 1; off < 64; off <<= 1) {
        unsigned n = __shfl_up(incl, off);
        if (lane >= off) incl += n;
    }
    unsigned run = incl - lsum;                 // relative to row start
    unsigned* prow = pbase + (size_t)gw * NPB + lane * 8;
    #pragma unroll
    for (int j = 0; j < 8; j++) { prow[j] = run; run += c[j]; }
    if (lane == 63) tot[gw] = (int)incl;
}

// Exclusive scan of 1564 totals -> shard bases (+ sentinel). One block.
__global__ __launch_bounds__(256) void scan_pass(
    const int* __restrict__ tot, int* __restrict__ sbase)
{
    __shared__ int ps[256];
    int t = threadIdx.x;
    int v[7];
    int s = 0;
    #pragma unroll
    for (int j = 0; j < 7; j++) {
        int i = t * 7 + j;
        v[j] = (i < 2 * NSH) ? tot[i] : 0;
        s += v[j];
    }
    ps[t] = s;
    __syncthreads();
    for (int off = 1; off < 256; off <<= 1) {
        int add = (t >= off) ? ps[t - off] : 0;
        __syncthreads();
        ps[t] += add;
        __syncthreads();
    }
    int run = (t == 0) ? 0 : ps[t - 1];
    #pragma unroll
    for (int j = 0; j < 7; j++) {
        int i = t * 7 + j;
        if (i < 2 * NSH) sbase[i] = run;
        run += v[j];
    }
    if (t == 255) sbase[2 * NSH] = run;
}

// Scatter edges into shard-segregated compact array: entry = (dst<<16)|src.
// lbase = relative pbase + sbase[row] (sbase is 6KB, L2-hot).
__global__ __launch_bounds__(256) void partition_pass(
    const int* __restrict__ ei0, int E0,
    const int* __restrict__ ei1, int E1,
    const unsigned* __restrict__ pbase, const int* __restrict__ sbase,
    unsigned* __restrict__ compact)             // [E0+E1] u32 (old bins slot)
{
    __shared__ unsigned lbase[NSH];
    __shared__ unsigned lrank[NSH];
    int local = blockIdx.x; int rel = 0;
    if (local >= NPB) { local -= NPB; rel = 1; }
    int pb = (local & 7) * (NPB / 8) + (local >> 3);
    const int* ei = rel ? ei1 : ei0;
    int E         = rel ? E1  : E0;
    int ce = (E + NPB - 1) / NPB;
    int lo = pb * ce, hi = min(lo + ce, E);

    for (int i = threadIdx.x; i < NSH; i += 256) {
        lbase[i] = pbase[((size_t)rel * NSH + i) * NPB + pb]
                 + (unsigned)sbase[rel * NSH + i];
        lrank[i] = 0;
    }
    __syncthreads();
    for (int t = lo + threadIdx.x; t < hi; t += 256) {
        int dst = ei[E + t];
        int src = ei[t];
        int s = dst >> 6;
        unsigned r = atomicAdd(&lrank[s], 1u);
        compact[lbase[s] + r] = ((unsigned)dst << 16) | (unsigned)src;
    }
}

// Fused bin+aggregate (R24-proven). Phase 1: LDS-sort the contiguous compact
// segment into per-node bins (CAP=32 + local ovf). Phase 2: uint2 gather —
// 16 lanes per 128B row, 4 rows/step, 2x unroll (8 rows in flight);
// quarter-reduce via shfl_xor(16,32); lanes 0-15 write the uint2 row.
__global__ __launch_bounds__(256) void aggregate_shard(
    const unsigned* __restrict__ compact, const int* __restrict__ sbase,
    const unsigned short* __restrict__ hb, unsigned short* __restrict__ agg)
{
    __shared__ unsigned short lbins[SHARD_W * CAP];   // 4KB
    __shared__ unsigned lcnt[SHARD_W];                // 256B
    __shared__ unsigned lovf[OVF_LDS];                // 4KB
    __shared__ unsigned lovf_cnt;

    int bid = blockIdx.x;                       // = rel*NSH + s
    int rel = bid / NSH;
    int s   = bid - rel * NSH;
    int tid = threadIdx.x;
    int lane = tid & 63;
    int qtr = lane >> 4;                        // 0..3: row-slot within wave
    int r   = lane & 15;                        // uint2 index within row
    int wid = tid >> 6;                         // 0..3

    if (tid < SHARD_W) lcnt[tid] = 0;
    if (tid == 0) lovf_cnt = 0;
    __syncthreads();

    // Phase 1: LDS bin (identical semantics to bin_pass, local ovf).
    int base = sbase[bid];
    int tt   = sbase[bid + 1] - base;
    for (int j = tid; j < tt; j += 256) {
        unsigned e = compact[base + j];
        int loc = (int)(e >> 16) & (SHARD_W - 1);
        unsigned rr = atomicAdd(&lcnt[loc], 1u);
        if (rr < CAP) {
            lbins[loc * CAP + rr] = (unsigned short)(e & 0xffffu);
        } else {
            unsigned o = atomicAdd(&lovf_cnt, 1u);
            if (o < OVF_LDS) lovf[o] = ((unsigned)loc << 16) | (e & 0xffffu);
        }
    }
    __syncthreads();

    // Phase 2: wide gather; wave w owns nodes w*16..w*16+15.
    const uint2* hb64 = (const uint2*)hb;       // row s = hb64[s*16 + r]
    uint2* agg64 = (uint2*)agg;
    for (int t = 0; t < 16; ++t) {
        int loc = wid * 16 + t;
        int d = (int)lcnt[loc];
        int m = min(d, CAP);
        int idx = 0;
        if (lane < m) idx = lbins[loc * CAP + lane];
        float a0=0.f, a1=0.f, a2=0.f, a3=0.f;       // even-step bank
        float b0=0.f, b1=0.f, b2=0.f, b3=0.f;       // odd-step bank
        int steps = (m + 3) >> 2;
        int j = 0;
        for (; j + 2 <= steps; j += 2) {
            int e0 = 4 * j + qtr;
            int e1 = 4 * (j + 1) + qtr;
            int s0 = __shfl(idx, e0 & 31);
            int s1 = __shfl(idx, e1 & 31);
            uint2 u0 = (e0 < m) ? hb64[(size_t)s0 * 16 + r] : make_uint2(0u, 0u);
            uint2 u1 = (e1 < m) ? hb64[(size_t)s1 * 16 + r] : make_uint2(0u, 0u);
            a0 += __uint_as_float(u0.x << 16); a1 += __uint_as_float(u0.x & 0xffff0000u);
            a2 += __uint_as_float(u0.y << 16); a3 += __uint_as_float(u0.y & 0xffff0000u);
            b0 += __uint_as_float(u1.x << 16); b1 += __uint_as_float(u1.x & 0xffff0000u);
            b2 += __uint_as_float(u1.y << 16); b3 += __uint_as_float(u1.y & 0xffff0000u);
        }
        for (; j < steps; ++j) {
            int e0 = 4 * j + qtr;
            int s0 = __shfl(idx, e0 & 31);
            uint2 u0 = (e0 < m) ? hb64[(size_t)s0 * 16 + r] : make_uint2(0u, 0u);
            a0 += __uint_as_float(u0.x << 16); a1 += __uint_as_float(u0.x & 0xffff0000u);
            a2 += __uint_as_float(u0.y << 16); a3 += __uint_as_float(u0.y & 0xffff0000u);
        }
        if (d > CAP) {                 // rare: this shard's local overflow
            int cnt = min((int)lovf_cnt, OVF_LDS);
            for (int e0 = 0; e0 < cnt; ++e0) {
                unsigned v = lovf[e0];
                if ((int)(v >> 16) == loc && qtr == 0) {
                    uint2 u = hb64[(size_t)(v & 0xffffu) * 16 + r];
                    a0 += __uint_as_float(u.x << 16); a1 += __uint_as_float(u.x & 0xffff0000u);
                    a2 += __uint_as_float(u.y << 16); a3 += __uint_as_float(u.y & 0xffff0000u);
                }
            }
        }
        a0 += b0; a1 += b1; a2 += b2; a3 += b3;
        a0 += __shfl_xor(a0, 16); a0 += __shfl_xor(a0, 32);
        a1 += __shfl_xor(a1, 16); a1 += __shfl_xor(a1, 32);
        a2 += __shfl_xor(a2, 16); a2 += __shfl_xor(a2, 32);
        a3 += __shfl_xor(a3, 16); a3 += __shfl_xor(a3, 32);
        int node = s * SHARD_W + loc;
        if (lane < 16 && node < NN) {
            float inv = 1.0f / (float)max(d, 1);
            uint2 o;
            o.x = (unsigned)f2bf(a0 * inv) | ((unsigned)f2bf(a1 * inv) << 16);
            o.y = (unsigned)f2bf(a2 * inv) | ((unsigned)f2bf(a3 * inv) << 16);
            agg64[((size_t)rel * NN + node) * 16 + r] = o;
        }
    }
}

// L0: h1b = bf16( relu(mean0@Wl0 + mean1@Wl1 + self@(Wr0+Wr1) + b) ).
#define RST 132
__global__ __launch_bounds__(256) void layer_gemm(
    const unsigned short* __restrict__ agg0, const unsigned short* __restrict__ agg1,
    const unsigned short* __restrict__ selfb,
    const float* __restrict__ Wl0, const float* __restrict__ Wl1,
    const float* __restrict__ Wr0, const float* __restrict__ Wr1,
    const float* __restrict__ b0, const float* __restrict__ b1,
    unsigned short* __restrict__ hb16)
{
    __shared__ float Wch[64 * 64];
    __shared__ float rowsT[64 * RST];
    __shared__ float bias[64];

    int tid = threadIdx.x;
    int base = blockIdx.x * 128;
    if (tid < 64) bias[tid] = b0[tid] + b1[tid];

    int j8 = (tid & 7) * 8;
    int n4 = (tid >> 3) * 4;

    float acc[4][8];
    #pragma unroll
    for (int i = 0; i < 4; i++)
        #pragma unroll
        for (int c = 0; c < 8; c++) acc[i][c] = 0.f;

    for (int chunk = 0; chunk < 3; chunk++) {
        const float* W = (chunk == 0) ? Wl0 : (chunk == 1) ? Wl1 : Wr0;
        const unsigned short* src = (chunk == 0) ? agg0 : (chunk == 1) ? agg1 : selfb;
        __syncthreads();
        #pragma unroll
        for (int r = 0; r < 4; r++) {
            int i = tid + 256 * r;
            float4 w = *(const float4*)&W[i * 4];
            if (chunk == 2) {
                float4 w2 = *(const float4*)&Wr1[i * 4];
                w.x += w2.x; w.y += w2.y; w.z += w2.z; w.w += w2.w;
            }
            *(float4*)&Wch[i * 4] = w;
        }
        #pragma unroll
        for (int r = 0; r < 8; r++) {
            int i = tid + 256 * r;
            int node = i >> 4;
            int k4 = (i & 15) * 4;
            int g = base + node;
            ushort4 u = make_ushort4(0, 0, 0, 0);
            if (g < NN) u = *(const ushort4*)&src[(size_t)g * 64 + k4];
            rowsT[(k4 + 0) * RST + node] = bf2f(u.x);
            rowsT[(k4 + 1) * RST + node] = bf2f(u.y);
            rowsT[(k4 + 2) * RST + node] = bf2f(u.z);
            rowsT[(k4 + 3) * RST + node] = bf2f(u.w);
        }
        __syncthreads();
        #pragma unroll 4
        for (int k = 0; k < 64; k++) {
            float4 wa = *(const float4*)&Wch[k * 64 + j8];
            float4 wb = *(const float4*)&Wch[k * 64 + j8 + 4];
            float4 rv = *(const float4*)&rowsT[k * RST + n4];
            float w[8] = {wa.x, wa.y, wa.z, wa.w, wb.x, wb.y, wb.z, wb.w};
            float rr[4] = {rv.x, rv.y, rv.z, rv.w};
            #pragma unroll
            for (int i = 0; i < 4; i++)
                #pragma unroll
                for (int c = 0; c < 8; c++)
                    acc[i][c] = fmaf(rr[i], w[c], acc[i][c]);
        }
    }

    #pragma unroll
    for (int i = 0; i < 4; i++) {
        int g = base + n4 + i;
        if (g < NN) {
            ushort4 p0, p1;
            p0.x = f2bf(fmaxf(acc[i][0] + bias[j8 + 0], 0.f));
            p0.y = f2bf(fmaxf(acc[i][1] + bias[j8 + 1], 0.f));
            p0.z = f2bf(fmaxf(acc[i][2] + bias[j8 + 2], 0.f));
            p0.w = f2bf(fmaxf(acc[i][3] + bias[j8 + 3], 0.f));
            p1.x = f2bf(fmaxf(acc[i][4] + bias[j8 + 4], 0.f));
            p1.y = f2bf(fmaxf(acc[i][5] + bias[j8 + 5], 0.f));
            p1.z = f2bf(fmaxf(acc[i][6] + bias[j8 + 6], 0.f));
            p1.w = f2bf(fmaxf(acc[i][7] + bias[j8 + 7], 0.f));
            *(ushort4*)&hb16[(size_t)g * 64 + j8]     = p0;
            *(ushort4*)&hb16[(size_t)g * 64 + j8 + 4] = p1;
        }
    }
}

// L1 + final fused: h2 tile in LDS, then out = h2 @ linW + linb.
__global__ __launch_bounds__(256) void layer_gemm_final(
    const unsigned short* __restrict__ agg0, const unsigned short* __restrict__ agg1,
    const unsigned short* __restrict__ selfb,
    const float* __restrict__ Wl0, const float* __restrict__ Wl1,
    const float* __restrict__ Wr0, const float* __restrict__ Wr1,
    const float* __restrict__ b0, const float* __restrict__ b1,
    const float* __restrict__ linW, const float* __restrict__ linb,
    float* __restrict__ out)
{
    __shared__ float Wch[64 * 64];
    __shared__ float rowsT[64 * RST];
    __shared__ float bias[64];

    int tid = threadIdx.x;
    int base = blockIdx.x * 128;
    if (tid < 64) bias[tid] = b0[tid] + b1[tid];

    int j8 = (tid & 7) * 8;
    int n4 = (tid >> 3) * 4;

    float acc[4][8];
    #pragma unroll
    for (int i = 0; i < 4; i++)
        #pragma unroll
        for (int c = 0; c < 8; c++) acc[i][c] = 0.f;

    for (int chunk = 0; chunk < 3; chunk++) {
        const float* W = (chunk == 0) ? Wl0 : (chunk == 1) ? Wl1 : Wr0;
        const unsigned short* src = (chunk == 0) ? agg0 : (chunk == 1) ? agg1 : selfb;
        __syncthreads();
        #pragma unroll
        for (int r = 0; r < 4; r++) {
            int i = tid + 256 * r;
            float4 w = *(const float4*)&W[i * 4];
            if (chunk == 2) {
                float4 w2 = *(const float4*)&Wr1[i * 4];
                w.x += w2.x; w.y += w2.y; w.z += w2.z; w.w += w2.w;
            }
            *(float4*)&Wch[i * 4] = w;
        }
        #pragma unroll
        for (int r = 0; r < 8; r++) {
            int i = tid + 256 * r;
            int node = i >> 4;
            int k4 = (i & 15) * 4;
            int g = base + node;
            ushort4 u = make_ushort4(0, 0, 0, 0);
            if (g < NN) u = *(const ushort4*)&src[(size_t)g * 64 + k4];
            rowsT[(k4 + 0) * RST + node] = bf2f(u.x);
            rowsT[(k4 + 1) * RST + node] = bf2f(u.y);
            rowsT[(k4 + 2) * RST + node] = bf2f(u.z);
            rowsT[(k4 + 3) * RST + node] = bf2f(u.w);
        }
        __syncthreads();
        #pragma unroll 4
        for (int k = 0; k < 64; k++) {
            float4 wa = *(const float4*)&Wch[k * 64 + j8];
            float4 wb = *(const float4*)&Wch[k * 64 + j8 + 4];
            float4 rv = *(const float4*)&rowsT[k * RST + n4];
            float w[8] = {wa.x, wa.y, wa.z, wa.w, wb.x, wb.y, wb.z, wb.w};
            float rr[4] = {rv.x, rv.y, rv.z, rv.w};
            #pragma unroll
            for (int i = 0; i < 4; i++)
                #pragma unroll
                for (int c = 0; c < 8; c++)
                    acc[i][c] = fmaf(rr[i], w[c], acc[i][c]);
        }
    }

    // relu epilogue into registers
    float o[4][8];
    #pragma unroll
    for (int i = 0; i < 4; i++)
        #pragma unroll
        for (int c = 0; c < 8; c++)
            o[i][c] = fmaxf(acc[i][c] + bias[j8 + c], 0.f);

    __syncthreads();   // everyone done reading Wch/rowsT/bias

    // restage: Wch <- linW (64x32), bias <- linb, rowsT <- h2 tile transposed
    #pragma unroll
    for (int r = 0; r < 2; r++) {
        int i = tid + 256 * r;   // 512 float4 = 2048 floats
        *(float4*)&Wch[i * 4] = *(const float4*)&linW[i * 4];
    }
    if (tid < 32) bias[tid] = linb[tid];
    #pragma unroll
    for (int i = 0; i < 4; i++)
        #pragma unroll
        for (int c = 0; c < 8; c++)
            rowsT[(j8 + c) * RST + (n4 + i)] = o[i][c];
    __syncthreads();

    // mini-GEMM: out[128 x 32] = h2_tile @ linW + linb
    int j4 = (tid & 7) * 4;
    float acc2[4][4];
    #pragma unroll
    for (int i = 0; i < 4; i++)
        #pragma unroll
        for (int c = 0; c < 4; c++) acc2[i][c] = 0.f;
    #pragma unroll 4
    for (int k = 0; k < 64; k++) {
        float4 w = *(const float4*)&Wch[k * 32 + j4];
        float4 rv = *(const float4*)&rowsT[k * RST + n4];
        float wr[4] = {w.x, w.y, w.z, w.w};
        float rr[4] = {rv.x, rv.y, rv.z, rv.w};
        #pragma unroll
        for (int i = 0; i < 4; i++)
            #pragma unroll
            for (int c = 0; c < 4; c++)
                acc2[i][c] = fmaf(rr[i], wr[c], acc2[i][c]);
    }
    #pragma unroll
    for (int i = 0; i < 4; i++) {
        int g = base + n4 + i;
        if (g < NN) {
            float4 ov;
            ov.x = acc2[i][0] + bias[j4 + 0];
            ov.y = acc2[i][1] + bias[j4 + 1];
            ov.z = acc2[i][2] + bias[j4 + 2];
            ov.w = acc2[i][3] + bias[j4 + 3];
            *(float4*)&out[(size_t)g * 32 + j4] = ov;
        }
    }
}

extern "C" void kernel_launch(void* const* d_in, const int* in_sizes, int n_in,
                              void* d_out, int out_size, void* d_ws, size_t ws_size,
                              hipStream_t stream)
{
    const float* x    = (const float*)d_in[0];
    const int*   ei0  = (const int*)d_in[1];
    const int*   ei1  = (const int*)d_in[2];
    const float* Wl   = (const float*)d_in[3];   // [2,2,64,64]
    const float* Wr   = (const float*)d_in[4];   // [2,2,64,64]
    const float* bl   = (const float*)d_in[5];   // [2,2,64]
    const float* linW = (const float*)d_in[6];   // [64,32]
    const float* linb = (const float*)d_in[7];   // [32]
    float* out = (float*)d_out;

    int E0 = in_sizes[1] / 2;
    int E1 = in_sizes[2] / 2;

    // Workspace (~32.4MB), R23 layout (compact outlives gemm0):
    // [compact 6.4MB | h1b 6.4MB | aggb 12.8MB | xb 6.4MB | tot/sbase 13KB]
    //   hist16 [2][NSH][NPB] 1.6MB aliases aggb+0      (dead before agg L0)
    //   pbase  [2][NSH][NPB] 3.2MB aliases aggb+1.6M   (dead after partition)
    unsigned*       compact = (unsigned*)d_ws;            // 1.6M u32 = 6.4MB
    unsigned short* h1b  = (unsigned short*)d_ws + (size_t)2 * NN * CAP;
    unsigned short* aggb = h1b + (size_t)NN * 64;
    unsigned short* agg0 = aggb;
    unsigned short* agg1 = aggb + (size_t)NN * 64;
    unsigned short* xb   = aggb + (size_t)2 * NN * 64;
    int*            tot   = (int*)(xb + (size_t)NN * 64);
    int*            sbase = tot + 2 * NSH;

    unsigned short* hist16 = aggb;
    unsigned*       pbase  = (unsigned*)(aggb + (size_t)2 * NSH * NPB);

    dim3 blk(256);
    int ggrid = (NN + 127) / 128;               // 391
    int wave_grid = (2 * NSH * 64 + 255) / 256; // 391: 1 wave/(rel,shard)

    // ---- shard-partition binning (bin fused into agg; total folded) ----
    shard_hist<<<2 * NPB, blk, 0, stream>>>(x, xb, ei0, E0, ei1, E1, hist16);
    blockbase_rel<<<wave_grid, blk, 0, stream>>>(hist16, pbase, tot);
    scan_pass<<<1, blk, 0, stream>>>(tot, sbase);
    partition_pass<<<2 * NPB, blk, 0, stream>>>(ei0, E0, ei1, E1, pbase, sbase,
                                                compact);

    // ---- Layer 0 (fused bin+aggregate from xb; h1b bf16 out) ----
    aggregate_shard<<<2 * NSH, blk, 0, stream>>>(compact, sbase, xb, aggb);
    layer_gemm<<<ggrid, blk, 0, stream>>>(agg0, agg1, xb,
        Wl + 0, Wl + 4096, Wr + 0, Wr + 4096, bl + 0, bl + 64, h1b);

    // ---- Layer 1 + final projection fused (h2 never materialized) ----
    aggregate_shard<<<2 * NSH, blk, 0, stream>>>(compact, sbase, h1b, aggb);
    layer_gemm_final<<<ggrid, blk, 0, stream>>>(agg0, agg1, h1b,
        Wl + 8192, Wl + 12288, Wr + 8192, Wr + 12288, bl + 128, bl + 192,
        linW, linb, out);
}